// Round 5
// baseline (155.965 us; speedup 1.0000x reference)
//
#include <hip/hip_runtime.h>
#include <math.h>

// Problem constants: D=8, H=64, W=64 -> 32768 pixels, 1024 gaussians
#define NG     1024
#define KD     256        // representation feature dim
#define NPIX   32768      // D*H*W
#define B1     512
#define B2     512
#define PSTR   12         // ws stride per gaussian (floats): 10 params + S + pad

#define LN2PI_15  2.7568155996140185f   // 1.5 * ln(2*pi)
#define LOG2E     1.4426950408889634f
#define SQH_L2E   0.8493218f            // sqrt(0.5 * log2(e))

__device__ __forceinline__ float softplus_f(float x) {
    // stable: max(x,0) + log1p(exp(-|x|)) — matches jax.nn.softplus
    return fmaxf(x, 0.0f) + log1pf(expf(-fabsf(x)));
}

__device__ __forceinline__ float exp2_fast(float x) {
#if __has_builtin(__builtin_amdgcn_exp2f)
    return __builtin_amdgcn_exp2f(x);     // v_exp_f32
#else
    float r; asm("v_exp_f32 %0, %1" : "=v"(r) : "v"(x)); return r;
#endif
}

// R5: two-kernel map-reduce. R1-R4 were all scratch-spill-bound (~+40us =
// 134MB spill write + read at 6.7TB/s). Here NO per-thread cache: kernel1
// computes params + sum S (recompute-exp pass, ~4us of trans-pipe), kernel2
// is a pure streaming-store normalize pass (~20 live VGPRs, write-roofline).
// No max pass (validated R3/R4: L>=log2 => lp<=-1.66, exp can't overflow,
// shift cancels in normalization). exp2 domain throughout.

// ---------------- kernel 1: params + partition sum ----------------
__global__ __launch_bounds__(B1)
void mvn_reduce_kernel(const float* __restrict__ rep,
                       const float* __restrict__ mean_W,
                       const float* __restrict__ mean_b,
                       const float* __restrict__ scale_W,
                       const float* __restrict__ scale_b,
                       float* __restrict__ ws)
{
    const int g = blockIdx.x;
    const int t = threadIdx.x;

    __shared__ float s_part[9][4];
    __shared__ float s_par[10];     // mx,my,mz, r00,L10,r11,L20,L21,r22s, c0
    __shared__ float s_red[8];

    // 9 dot-products of length 256 (threads 0..255 = waves 0..3)
    if (t < KD) {
        float r = rep[g * KD + t];
        float acc9[9];
        #pragma unroll
        for (int k = 0; k < 3; ++k) acc9[k]     = r * mean_W[k * KD + t];
        #pragma unroll
        for (int k = 0; k < 6; ++k) acc9[3 + k] = r * scale_W[k * KD + t];
        #pragma unroll
        for (int k = 0; k < 9; ++k) {
            float v = acc9[k];
            #pragma unroll
            for (int off = 32; off >= 1; off >>= 1)
                v += __shfl_xor(v, off, 64);
            if ((t & 63) == 0) s_part[k][t >> 6] = v;
        }
    }
    __syncthreads();
    if (t == 0) {
        float dsum[9];
        #pragma unroll
        for (int k = 0; k < 9; ++k)
            dsum[k] = (s_part[k][0] + s_part[k][1]) + (s_part[k][2] + s_part[k][3]);
        float mx = dsum[0] + mean_b[0];
        float my = dsum[1] + mean_b[1];
        float mz = dsum[2] + mean_b[2];
        float s0 = softplus_f(dsum[3] + scale_b[0]) + 1e-6f;
        float s1 = softplus_f(dsum[4] + scale_b[1]) + 1e-6f;
        float s2 = softplus_f(dsum[5] + scale_b[2]) + 1e-6f;
        float s3 = softplus_f(dsum[6] + scale_b[3]) + 1e-6f;
        float s4 = softplus_f(dsum[7] + scale_b[4]) + 1e-6f;
        float s5 = softplus_f(dsum[8] + scale_b[5]) + 1e-6f;
        float L00 = softplus_f(s0);
        float L11 = softplus_f(s2);
        float L22 = softplus_f(s5);
        float par[10];
        par[0] = mx; par[1] = my; par[2] = mz;
        par[3] = 1.0f / L00;
        par[4] = s1;                          // L10
        par[5] = 1.0f / L11;
        par[6] = s3;                          // L20
        par[7] = s4;                          // L21
        par[8] = SQH_L2E / L22;               // r22s
        par[9] = -LOG2E * (logf(L00) + logf(L11) + logf(L22) + LN2PI_15);  // c0
        #pragma unroll
        for (int k = 0; k < 10; ++k) { s_par[k] = par[k]; ws[g * PSTR + k] = par[k]; }
    }
    __syncthreads();
    const float mx  = s_par[0], my  = s_par[1], mz  = s_par[2];
    const float r00 = s_par[3], L10 = s_par[4], r11 = s_par[5];
    const float L20 = s_par[6], L21 = s_par[7], r22s = s_par[8];
    const float c0  = s_par[9];

    // per-thread consts: x = 4*(t&15)+k fixed; fy = (t>>4) + 32*fsel
    const float xb = (float)(4 * (t & 15)) - 31.5f - mx;
    const float f0 = (float)(t >> 4);
    float urs[8], base[8];
    #pragma unroll
    for (int k = 0; k < 4; ++k) {
        float y0  = (xb + (float)k) * r00;
        float y0s = y0 * SQH_L2E;
        float b0  = fmaf(-y0s, y0s, c0);
        float dzk = fmaf(-L20, y0, -3.5f - mz);
        float dyk = fmaf(-L10, y0, -31.5f - my);
        #pragma unroll
        for (int f = 0; f < 2; ++f) {
            float py  = f0 + (float)(32 * f);
            float y1  = (py + dyk) * r11;
            float y1s = y1 * SQH_L2E;
            base[k*2+f] = fmaf(-y1s, y1s, b0);
            urs [k*2+f] = fmaf(-L21, y1, dzk) * r22s;
        }
    }

    // sum of exp2 over this thread's 64 pixels (recompute, nothing cached)
    float acc0 = 0.f, acc1 = 0.f, acc2 = 0.f, acc3 = 0.f;
    #pragma unroll
    for (int i = 0; i < 16; ++i) {
        const int   fs = i & 1;
        const float fz = (float)(i >> 1);
        { float y2s = fmaf(fz, r22s, urs[0+fs]); acc0 += exp2_fast(fmaf(-y2s, y2s, base[0+fs])); }
        { float y2s = fmaf(fz, r22s, urs[2+fs]); acc1 += exp2_fast(fmaf(-y2s, y2s, base[2+fs])); }
        { float y2s = fmaf(fz, r22s, urs[4+fs]); acc2 += exp2_fast(fmaf(-y2s, y2s, base[4+fs])); }
        { float y2s = fmaf(fz, r22s, urs[6+fs]); acc3 += exp2_fast(fmaf(-y2s, y2s, base[6+fs])); }
    }
    float lsum = (acc0 + acc1) + (acc2 + acc3);
    #pragma unroll
    for (int off = 32; off >= 1; off >>= 1)
        lsum += __shfl_xor(lsum, off, 64);
    if ((t & 63) == 0) s_red[t >> 6] = lsum;
    __syncthreads();
    if (t == 0) {
        float S = 0.0f;
        #pragma unroll
        for (int k = 0; k < 8; ++k) S += s_red[k];
        ws[g * PSTR + 10] = S;
    }
}

// ---------------- kernel 2: normalize + streaming store ----------------
__global__ __launch_bounds__(B2)
void mvn_write_kernel(const float* __restrict__ ws, float* __restrict__ out)
{
    const int b    = blockIdx.x;        // 0..2047
    const int g    = b >> 1;
    const int half = b & 1;             // z-halves 0..3 / 4..7
    const int t    = threadIdx.x;

    const float* P = ws + g * PSTR;
    const float mx  = P[0], my  = P[1], mz  = P[2];
    const float r00 = P[3], L10 = P[4], r11 = P[5];
    const float L20 = P[6], L21 = P[7], r22s = P[8];
    const float c0n = P[9] - log2f(P[10] + 1e-10f);   // normalization folded in

    // pixels p = 16384*half + 4t + 2048*i, i<8:
    //   x = 4*(t&15)+k (fixed), fy = (t>>4) + 32*(i&1), fz = 4*half + (i>>1)
    const float xb = (float)(4 * (t & 15)) - 31.5f - mx;
    const float f0 = (float)(t >> 4);
    float urs[8], base[8];
    #pragma unroll
    for (int k = 0; k < 4; ++k) {
        float y0  = (xb + (float)k) * r00;
        float y0s = y0 * SQH_L2E;
        float b0  = fmaf(-y0s, y0s, c0n);
        float dzk = fmaf(-L20, y0, -3.5f - mz);
        float dyk = fmaf(-L10, y0, -31.5f - my);
        #pragma unroll
        for (int f = 0; f < 2; ++f) {
            float py  = f0 + (float)(32 * f);
            float y1  = (py + dyk) * r11;
            float y1s = y1 * SQH_L2E;
            base[k*2+f] = fmaf(-y1s, y1s, b0);
            urs [k*2+f] = fmaf(-L21, y1, dzk) * r22s;
        }
    }

    float4* op4 = (float4*)(out + (size_t)g * NPIX) + half * 4096 + t;
    #pragma unroll
    for (int i = 0; i < 8; ++i) {
        const int   fs = i & 1;
        const float fz = (float)(4 * half + (i >> 1));
        float4 o;
        { float y2s = fmaf(fz, r22s, urs[0+fs]); o.x = exp2_fast(fmaf(-y2s, y2s, base[0+fs])); }
        { float y2s = fmaf(fz, r22s, urs[2+fs]); o.y = exp2_fast(fmaf(-y2s, y2s, base[2+fs])); }
        { float y2s = fmaf(fz, r22s, urs[4+fs]); o.z = exp2_fast(fmaf(-y2s, y2s, base[4+fs])); }
        { float y2s = fmaf(fz, r22s, urs[6+fs]); o.w = exp2_fast(fmaf(-y2s, y2s, base[6+fs])); }
        op4[i * 512] = o;
    }
}

extern "C" void kernel_launch(void* const* d_in, const int* in_sizes, int n_in,
                              void* d_out, int out_size, void* d_ws, size_t ws_size,
                              hipStream_t stream) {
    const float* rep     = (const float*)d_in[0];
    const float* mean_W  = (const float*)d_in[1];
    const float* mean_b  = (const float*)d_in[2];
    const float* scale_W = (const float*)d_in[3];
    const float* scale_b = (const float*)d_in[4];
    float* out = (float*)d_out;
    float* ws  = (float*)d_ws;   // needs NG*PSTR*4 = 48 KB

    hipLaunchKernelGGL(mvn_reduce_kernel, dim3(NG), dim3(B1), 0, stream,
                       rep, mean_W, mean_b, scale_W, scale_b, ws);
    hipLaunchKernelGGL(mvn_write_kernel, dim3(2 * NG), dim3(B2), 0, stream,
                       ws, out);
}